// Round 11
// baseline (11415.774 us; speedup 1.0000x reference)
//
#include <hip/hip_runtime.h>
#include <math.h>

// ---------------------------------------------------------------------------
// 2-layer tanh RNN scan, B=128, T=1024, H=768.  Persistent kernel, 256 WGs.
// Round-11: LATENCY HIDING BY GROUP MULTIPLEXING.  B split into 16 groups of
// 8 rows; each WG serves the SAME role (same columns -> same weight regs) in
// TWO groups (gA = wg>>5, gB = gA+8), alternating every step.  While one
// group's flag/data round trips propagate, the WG computes the other group.
// Per-group structure, coherence primitives, and dep graph = round-10
// (verified): agent-scope st_ag/ld_ag, wave-0 poll + acquire fence + sync,
// 4-slot h1 / 2-slot h2 / 4-slot P, off-path out-reduce gating the h1 slots.
// New: all flag checks CACHED (wave-0 poll result broadcast via LDS; a
// satisfied check costs zero memory ops).  M=8 uses the 16-row MFMA tiles
// with lanes l15>=8 masked to zero fragments (masked loads, masked stores).
// Numerics: bf16 (hi,lo) pairs, 3-product MFMA, fp32 accumulate (proven).
// ---------------------------------------------------------------------------

typedef short s16x8 __attribute__((ext_vector_type(8)));
typedef float fx4   __attribute__((ext_vector_type(4)));

#define NWG    256
#define T_LEN  1024
#define H      768
#define NGRP   16
#define GROWS  8

// per-group ws layout (bytes)
#define GRP_BASE   4096
#define G_FL1 0               // u32[8]
#define G_FH2 128             // u32[24]
#define G_PB  512             // float[4][8][2][24] = 6144B
#define G_H1  8192            // 4 slots x {hi,lo} x 12288B
#define G_H2  106496          // 2 slots x {hi,lo} x 12288B
#define GRP_STRIDE 155648
#define HB8   12288           // 8*768*2B
#define WS_TOTAL (GRP_BASE + NGRP * GRP_STRIDE)

__device__ __forceinline__ unsigned short f2bf(float x) {
    unsigned u = __float_as_uint(x);
    unsigned r = (u + 0x7FFFu + ((u >> 16) & 1u)) >> 16;   // RNE
    return (unsigned short)r;
}
__device__ __forceinline__ float bf2f(unsigned short b) {
    return __uint_as_float(((unsigned)b) << 16);
}
__device__ __forceinline__ fx4 mfma16(s16x8 a, s16x8 b, fx4 c) {
    return __builtin_amdgcn_mfma_f32_16x16x32_bf16(a, b, c, 0, 0, 0);
}

// ---- proven agent-scope primitives -----------------------------------------
__device__ __forceinline__ void st_ag(unsigned* p, unsigned v) {
    __hip_atomic_store(p, v, __ATOMIC_RELAXED, __HIP_MEMORY_SCOPE_AGENT);
}
__device__ __forceinline__ unsigned ld_ag(const unsigned* p) {
    return __hip_atomic_load(p, __ATOMIC_RELAXED, __HIP_MEMORY_SCOPE_AGENT);
}
__device__ __forceinline__ void acq_ag() {
    __builtin_amdgcn_fence(__ATOMIC_ACQUIRE, "agent");
}

__device__ __forceinline__ void load_wfrag(const float* __restrict__ W,
                                           int col, int kk, s16x8& hi, s16x8& lo) {
    const float* p = W + (long)col * H + kk;
#pragma unroll
    for (int j = 0; j < 8; j++) {
        float w = p[j];
        unsigned short h = f2bf(w);
        float r = w - bf2f(h);
        hi[j] = (short)h;
        lo[j] = (short)f2bf(r);
    }
}

__device__ __forceinline__ void ld6(const unsigned short* p, s16x8 (&d)[6]) {
#pragma unroll
    for (int ks = 0; ks < 6; ks++)
        d[ks] = *reinterpret_cast<const s16x8*>(p + ks * 32);
}

__device__ __forceinline__ unsigned wave_min(unsigned v) {
#pragma unroll
    for (int o = 32; o; o >>= 1) {
        unsigned u = (unsigned)__shfl_xor((int)v, o);
        v = v < u ? v : u;
    }
    return v;
}

// Wave-0 poll; broadcast observed min via LDS; optional acquire fence.
__device__ __forceinline__ unsigned waitn(const unsigned* f, int n, unsigned T,
                                          int tid, bool acq, volatile unsigned* sh) {
    if (tid < 64) {
        int l = tid < n ? tid : n - 1;
        unsigned m;
        long spin = 0;
        for (;;) {
            m = wave_min(ld_ag(f + l));
            if (m >= T) break;
            __builtin_amdgcn_s_sleep(1);
            if (++spin > (1L << 20)) break;   // failsafe
        }
        if (tid == 0) { if (acq) acq_ag(); *sh = m; }
    }
    __syncthreads();
    return *sh;
}

#define DRAIN() do { asm volatile("s_waitcnt vmcnt(0)" ::: "memory"); __syncthreads(); } while (0)

__global__ __launch_bounds__(256, 1) void rnn_persist(
    const float* __restrict__ x,
    const float* __restrict__ Wih1, const float* __restrict__ Whh1,
    const float* __restrict__ bih1, const float* __restrict__ bhh1,
    const float* __restrict__ Wih2, const float* __restrict__ Whh2,
    const float* __restrict__ bih2, const float* __restrict__ bhh2,
    const float* __restrict__ Wlin, const float* __restrict__ blin,
    float* __restrict__ out, unsigned char* __restrict__ ws)
{
    const int wg = blockIdx.x;
    const int tid = threadIdx.x;
    const int lane = tid & 63;
    const int w = tid >> 6;          // wave 0..3, K range [w*192, +192)
    const int l15 = lane & 15;
    const int lk8 = (lane >> 4) * 8;

    const int lrank = wg & 31;       // role 0..31
    const int g0 = wg >> 5;          // serves groups g0 and g0+8

    __shared__ float red[4][16][97];
    __shared__ unsigned shm[4];

    unsigned* fL1[2]; unsigned* fH2[2]; float* Pb[2];
    unsigned char* h1b[2]; unsigned char* h2b[2]; int rowb[2];
#pragma unroll
    for (int i = 0; i < 2; i++) {
        int g = g0 + i * 8;
        unsigned char* gb = ws + GRP_BASE + (size_t)g * GRP_STRIDE;
        fL1[i] = (unsigned*)(gb + G_FL1);
        fH2[i] = (unsigned*)(gb + G_FH2);
        Pb[i]  = (float*)(gb + G_PB);
        h1b[i] = gb + G_H1;
        h2b[i] = gb + G_H2;
        rowb[i] = g * GROWS;
    }

    const int kb0 = w * 192;
    const s16x8 z8 = {0, 0, 0, 0, 0, 0, 0, 0};

    if (lrank < 8) {
        // ========================= L1 role (x2 groups) =======================
        const int c = lrank;
        const int col0 = c * 96;

        s16x8 whi[6][6], wlo[6][6];
#pragma unroll
        for (int ks = 0; ks < 6; ks++)
#pragma unroll
            for (int nt = 0; nt < 6; nt++)
                load_wfrag(Whh1, col0 + nt * 16 + l15, kb0 + ks * 32 + lk8,
                           whi[ks][nt], wlo[ks][nt]);

        const int er = tid >> 4;                // 0..15, valid < 8
        const int ec0 = (tid & 15) * 6;
        float bs[6], wi0[6], wi1[6];
#pragma unroll
        for (int j = 0; j < 6; j++) {
            int cg = col0 + ec0 + j;
            bs[j] = bih1[cg] + bhh1[cg];
            wi0[j] = Wih1[cg * 2 + 0];
            wi1[j] = Wih1[cg * 2 + 1];
        }
        const int oo_ = (tid >> 5) & 1;          // tid<64: out channel
        const int oj = tid & 31;
        const float blv = blin[oo_];

        unsigned fl1c[2] = {0, 0}, fh2c[2] = {0, 0};

        for (int t = 0; t < T_LEN; t++) {
#pragma unroll
            for (int i = 0; i < 2; i++) {
                // off-path: gate (h1-slot guard) + out(t-3)
                if (t >= 3) {
                    if (fh2c[i] < (unsigned)(t - 2))
                        fh2c[i] = waitn(fH2[i], 24, (unsigned)(t - 2), tid, false, &shm[0]);
                    if (tid < 64) {
                        float p = 0.f;
                        if (oj < 24)
                            p = __uint_as_float(ld_ag((const unsigned*)
                                (Pb[i] + ((((t - 3) & 3) * 8 + c) * 2 + oo_) * 24 + oj)));
#pragma unroll
                        for (int o = 16; o; o >>= 1) p += __shfl_down(p, o, 32);
                        if (oj == 0) out[(rowb[i] + c) * 2048 + oo_ * 1024 + (t - 3)] = p + blv;
                    }
                }

                if (t && fl1c[i] < (unsigned)t)
                    fl1c[i] = waitn(fL1[i], 8, (unsigned)t, tid, true, &shm[1]);

                float x0 = 0.f, x1 = 0.f;
                if (er < 8) {
                    x0 = x[(rowb[i] + er) * 2048 + t];
                    x1 = x[(rowb[i] + er) * 2048 + 1024 + t];
                }

                const unsigned short* Hh = (const unsigned short*)(h1b[i] + ((t + 3) & 3) * 2 * HB8);
                const unsigned short* Hl = (const unsigned short*)(h1b[i] + ((t + 3) & 3) * 2 * HB8 + HB8);
                s16x8 ah[6], al[6];
                if (l15 < 8) {
                    ld6(Hh + l15 * H + kb0 + lk8, ah);
                    ld6(Hl + l15 * H + kb0 + lk8, al);
                } else {
#pragma unroll
                    for (int ks = 0; ks < 6; ks++) { ah[ks] = z8; al[ks] = z8; }
                }

                fx4 acc[6];
#pragma unroll
                for (int nt = 0; nt < 6; nt++) acc[nt] = fx4{0.f, 0.f, 0.f, 0.f};
#pragma unroll
                for (int ks = 0; ks < 6; ks++)
#pragma unroll
                    for (int nt = 0; nt < 6; nt++) {
                        acc[nt] = mfma16(ah[ks], whi[ks][nt], acc[nt]);
                        acc[nt] = mfma16(ah[ks], wlo[ks][nt], acc[nt]);
                        acc[nt] = mfma16(al[ks], whi[ks][nt], acc[nt]);
                    }

#pragma unroll
                for (int nt = 0; nt < 6; nt++)
#pragma unroll
                    for (int ii = 0; ii < 4; ii++)
                        red[w][(lane >> 4) * 4 + ii][nt * 16 + l15] = acc[nt][ii];
                __syncthreads();

                if (er < 8) {
                    unsigned hw[3], lw[3];
#pragma unroll
                    for (int jj = 0; jj < 3; jj++) {
                        unsigned hp = 0, lp = 0;
#pragma unroll
                        for (int k = 0; k < 2; k++) {
                            int j = jj * 2 + k;
                            int cc = ec0 + j;
                            float v = red[0][er][cc] + red[1][er][cc] + red[2][er][cc] + red[3][er][cc];
                            v += x0 * wi0[j] + x1 * wi1[j] + bs[j];
                            v = tanhf(v);
                            unsigned short hb = f2bf(v);
                            unsigned short lb = f2bf(v - bf2f(hb));
                            hp |= ((unsigned)hb) << (16 * k);
                            lp |= ((unsigned)lb) << (16 * k);
                        }
                        hw[jj] = hp; lw[jj] = lp;
                    }
                    unsigned* Dh = (unsigned*)(h1b[i] + (t & 3) * 2 * HB8) + ((long)er * H + col0 + ec0) / 2;
                    unsigned* Dl = (unsigned*)(h1b[i] + (t & 3) * 2 * HB8 + HB8) + ((long)er * H + col0 + ec0) / 2;
                    st_ag(Dh + 0, hw[0]); st_ag(Dh + 1, hw[1]); st_ag(Dh + 2, hw[2]);
                    st_ag(Dl + 0, lw[0]); st_ag(Dl + 1, lw[1]); st_ag(Dl + 2, lw[2]);
                }

                DRAIN();
                if (tid == 0) st_ag(fL1[i] + c, (unsigned)(t + 1));
            }
        }

        // tails: out(T-3..T-1) for both groups
#pragma unroll
        for (int i = 0; i < 2; i++) {
            waitn(fH2[i], 24, (unsigned)T_LEN, tid, false, &shm[2]);
            if (tid < 64) {
#pragma unroll
                for (int par = 0; par < 3; par++) {
                    int tt = T_LEN - 3 + par;
                    float p = 0.f;
                    if (oj < 24)
                        p = __uint_as_float(ld_ag((const unsigned*)
                            (Pb[i] + (((tt & 3) * 8 + c) * 2 + oo_) * 24 + oj)));
#pragma unroll
                    for (int o = 16; o; o >>= 1) p += __shfl_down(p, o, 32);
                    if (oj == 0) out[(rowb[i] + c) * 2048 + oo_ * 1024 + tt] = p + blv;
                }
            }
            __syncthreads();
        }
    } else {
        // ========================= L2 role (x2 groups) =======================
        const int q = lrank - 8;         // 0..23
        const int col0 = q * 32;

        s16x8 ghi[2][6], glo[2][6], ihi[2][6], ilo[2][6];
#pragma unroll
        for (int nt = 0; nt < 2; nt++)
#pragma unroll
            for (int ks = 0; ks < 6; ks++) {
                load_wfrag(Whh2, col0 + nt * 16 + l15, kb0 + ks * 32 + lk8, ghi[nt][ks], glo[nt][ks]);
                load_wfrag(Wih2, col0 + nt * 16 + l15, kb0 + ks * 32 + lk8, ihi[nt][ks], ilo[nt][ks]);
            }

        const int er = tid >> 4;             // valid < 8
        const int ec0 = (tid & 15) * 2;
        const float bsA = bih2[col0 + ec0] + bhh2[col0 + ec0];
        const float bsB = bih2[col0 + ec0 + 1] + bhh2[col0 + ec0 + 1];

        const int ro = tid >> 1, oo = tid & 1;   // tid<16: P-partial dot
        float wl[32];
        if (tid < 16) {
#pragma unroll
            for (int cc = 0; cc < 32; cc++) wl[cc] = Wlin[oo * H + col0 + cc];
        }

        unsigned fh2c[2] = {0, 0}, fl1c[2] = {0, 0};

        for (int t = 0; t < T_LEN; t++) {
#pragma unroll
            for (int i = 0; i < 2; i++) {
                if (t && fh2c[i] < (unsigned)t)
                    fh2c[i] = waitn(fH2[i], 24, (unsigned)t, tid, true, &shm[2]);

                // phase 1: h2(t-1) @ W_hh2^T
                const unsigned short* Gh = (const unsigned short*)(h2b[i] + ((t + 1) & 1) * 2 * HB8);
                const unsigned short* Gl = (const unsigned short*)(h2b[i] + ((t + 1) & 1) * 2 * HB8 + HB8);
                s16x8 ah[6], al[6];
                if (l15 < 8) {
                    ld6(Gh + l15 * H + kb0 + lk8, ah);
                    ld6(Gl + l15 * H + kb0 + lk8, al);
                } else {
#pragma unroll
                    for (int ks = 0; ks < 6; ks++) { ah[ks] = z8; al[ks] = z8; }
                }

                fx4 a2[2];
                a2[0] = fx4{0.f, 0.f, 0.f, 0.f};
                a2[1] = fx4{0.f, 0.f, 0.f, 0.f};
#pragma unroll
                for (int ks = 0; ks < 6; ks++)
#pragma unroll
                    for (int nt = 0; nt < 2; nt++) {
                        a2[nt] = mfma16(ah[ks], ghi[nt][ks], a2[nt]);
                        a2[nt] = mfma16(ah[ks], glo[nt][ks], a2[nt]);
                        a2[nt] = mfma16(al[ks], ghi[nt][ks], a2[nt]);
                    }

                if (fl1c[i] < (unsigned)(t + 1))
                    fl1c[i] = waitn(fL1[i], 8, (unsigned)(t + 1), tid, true, &shm[3]);

                // phase 3: += h1(t) @ W_ih2^T
                const unsigned short* Hh = (const unsigned short*)(h1b[i] + (t & 3) * 2 * HB8);
                const unsigned short* Hl = (const unsigned short*)(h1b[i] + (t & 3) * 2 * HB8 + HB8);
                if (l15 < 8) {
                    ld6(Hh + l15 * H + kb0 + lk8, ah);
                    ld6(Hl + l15 * H + kb0 + lk8, al);
                } else {
#pragma unroll
                    for (int ks = 0; ks < 6; ks++) { ah[ks] = z8; al[ks] = z8; }
                }
#pragma unroll
                for (int ks = 0; ks < 6; ks++)
#pragma unroll
                    for (int nt = 0; nt < 2; nt++) {
                        a2[nt] = mfma16(ah[ks], ihi[nt][ks], a2[nt]);
                        a2[nt] = mfma16(ah[ks], ilo[nt][ks], a2[nt]);
                        a2[nt] = mfma16(al[ks], ihi[nt][ks], a2[nt]);
                    }

#pragma unroll
                for (int nt = 0; nt < 2; nt++)
#pragma unroll
                    for (int ii = 0; ii < 4; ii++)
                        red[w][(lane >> 4) * 4 + ii][nt * 16 + l15] = a2[nt][ii];
                __syncthreads();

                if (er < 8) {
                    float v0 = red[0][er][ec0] + red[1][er][ec0] + red[2][er][ec0] + red[3][er][ec0] + bsA;
                    float v1 = red[0][er][ec0 + 1] + red[1][er][ec0 + 1] + red[2][er][ec0 + 1] + red[3][er][ec0 + 1] + bsB;
                    v0 = tanhf(v0); v1 = tanhf(v1);
                    unsigned short hb0 = f2bf(v0), hb1 = f2bf(v1);
                    unsigned hp = ((unsigned)hb0) | (((unsigned)hb1) << 16);
                    unsigned lp = ((unsigned)f2bf(v0 - bf2f(hb0))) | (((unsigned)f2bf(v1 - bf2f(hb1))) << 16);
                    unsigned* Dh = (unsigned*)(h2b[i] + (t & 1) * 2 * HB8) + ((long)er * H + col0 + ec0) / 2;
                    unsigned* Dl = (unsigned*)(h2b[i] + (t & 1) * 2 * HB8 + HB8) + ((long)er * H + col0 + ec0) / 2;
                    st_ag(Dh, hp);
                    st_ag(Dl, lp);
                    red[0][er][ec0] = v0;
                    red[0][er][ec0 + 1] = v1;
                }
                __syncthreads();

                if (tid < 16) {
                    float s = 0.f;
#pragma unroll
                    for (int cc = 0; cc < 32; cc++) s += red[0][ro][cc] * wl[cc];
                    st_ag((unsigned*)&Pb[i][(((t & 3) * 8 + ro) * 2 + oo) * 24 + q],
                          __float_as_uint(s));
                }

                DRAIN();
                if (tid == 0) st_ag(fH2[i] + q, (unsigned)(t + 1));
            }
        }
    }
}

extern "C" void kernel_launch(void* const* d_in, const int* in_sizes, int n_in,
                              void* d_out, int out_size, void* d_ws, size_t ws_size,
                              hipStream_t stream) {
    const float* x    = (const float*)d_in[0];
    const float* Wih1 = (const float*)d_in[1];
    const float* Whh1 = (const float*)d_in[2];
    const float* bih1 = (const float*)d_in[3];
    const float* bhh1 = (const float*)d_in[4];
    const float* Wih2 = (const float*)d_in[5];
    const float* Whh2 = (const float*)d_in[6];
    const float* bih2 = (const float*)d_in[7];
    const float* bhh2 = (const float*)d_in[8];
    const float* Wlin = (const float*)d_in[9];
    const float* blin = (const float*)d_in[10];

    // Zero flags + h-state (initial h = 0).  P fully written before read;
    // out fully overwritten by owned stores.
    hipMemsetAsync(d_ws, 0, WS_TOTAL, stream);

    rnn_persist<<<NWG, 256, 0, stream>>>(x, Wih1, Whh1, bih1, bhh1,
                                         Wih2, Whh2, bih2, bhh2,
                                         Wlin, blin, (float*)d_out,
                                         (unsigned char*)d_ws);
}